// Round 3
// baseline (2564.338 us; speedup 1.0000x reference)
//
#include <hip/hip_runtime.h>
#include <math.h>

typedef unsigned short u16;
typedef u16 ushort8 __attribute__((ext_vector_type(8)));
typedef __bf16 bf16x8 __attribute__((ext_vector_type(8)));
typedef float floatx4 __attribute__((ext_vector_type(4)));

__device__ __forceinline__ float bf2f(u16 u) {
  union { unsigned int i; float f; } v; v.i = ((unsigned int)u) << 16; return v.f;
}
__device__ __forceinline__ u16 f2bf(float f) {
  union { float f; unsigned int i; } v; v.f = f;
  return (u16)((v.i + 0x7fffu + ((v.i >> 16) & 1u)) >> 16);
}

#define CEILDIV(a, b) (((a) + (b) - 1) / (b))

// ---------------- transpose+convert: W[K][N] (f32) -> Wt[N][K] (bf16) ----------------
__global__ void k_transpose(const float* __restrict__ W, u16* __restrict__ Wt, int K, int N) {
  int t = blockIdx.x * blockDim.x + threadIdx.x;
  if (t >= K * N) return;
  int n = t / K, k = t - n * K;
  Wt[t] = f2bf(W[k * N + n]);
}

// ---------------- CSR build ----------------
__global__ void k_hist(const int* __restrict__ dst, int E, int* __restrict__ cnt) {
  int t = blockIdx.x * blockDim.x + threadIdx.x;
  if (t < E) atomicAdd(&cnt[dst[t]], 1);
}

__global__ __launch_bounds__(1024) void k_scan(const int* __restrict__ cnt, int* __restrict__ rp, int n) {
  __shared__ int sm[1024];
  int t = threadIdx.x;
  int chunk = (n + 1023) >> 10;
  int s = t * chunk, e = min(n, s + chunk);
  int loc = 0;
  for (int i = s; i < e; ++i) loc += cnt[i];
  sm[t] = loc;
  __syncthreads();
  for (int off = 1; off < 1024; off <<= 1) {
    int v = (t >= off) ? sm[t - off] : 0;
    __syncthreads();
    sm[t] += v;
    __syncthreads();
  }
  int base = sm[t] - loc;
  for (int i = s; i < e; ++i) { rp[i] = base; base += cnt[i]; }
  if (t == 1023) rp[n] = sm[1023];
}

__global__ void k_scatter(const int* __restrict__ dst, int E, const int* __restrict__ rp,
                          int* __restrict__ cur, int* __restrict__ eidx) {
  int t = blockIdx.x * blockDim.x + threadIdx.x;
  if (t >= E) return;
  int d = dst[t];
  int p = atomicAdd(&cur[d], 1);
  eidx[rp[d] + p] = t;
}

// ---------------- GEMM: C[M,N] = A[M,K] @ Bt[N,K]^T (+bias), fp32 acc ----------------
// A: f32 or bf16 (templated). Bt: bf16. bias: f32.
// mode 0: store bf16 to Cb. mode 1: tanh(C+bias) column-sum -> atomicAdd colsum[N]. mode 2: store f32 to Cf.
#define BM 128
#define BN 128
#define BK 32
template <typename AT>
__global__ __launch_bounds__(256) void k_gemm(
    const AT* __restrict__ A, const u16* __restrict__ Bt,
    const float* __restrict__ bias, u16* __restrict__ Cb, float* __restrict__ Cf,
    float* __restrict__ colsum, int M, int N, int K, int mode) {
  __shared__ u16 As[BM][BK + 8];
  __shared__ u16 Bs[BN][BK + 8];
  int tid = threadIdx.x;
  int lane = tid & 63;
  int wid = tid >> 6;
  int wm = wid >> 1, wn = wid & 1;
  int quad = lane >> 4, l16 = lane & 15;
  int m0 = blockIdx.x * BM, n0 = blockIdx.y * BN;

  floatx4 acc[4][4];
#pragma unroll
  for (int i = 0; i < 4; i++)
#pragma unroll
    for (int j = 0; j < 4; j++) acc[i][j] = (floatx4){0.f, 0.f, 0.f, 0.f};

  int r_s = tid >> 2;
  int c_s = (tid & 3) * 8;

  for (int k0 = 0; k0 < K; k0 += BK) {
#pragma unroll
    for (int it = 0; it < 2; ++it) {
      int r = r_s + it * 64;
      int gm = m0 + r;
      u16 tmp[8];
      if (gm < M) {
        const AT* ap = A + (size_t)gm * K + k0 + c_s;
#pragma unroll
        for (int j = 0; j < 8; j++) {
          if constexpr (sizeof(AT) == 4) tmp[j] = f2bf(((const float*)ap)[j]);
          else tmp[j] = ((const u16*)ap)[j];
        }
      } else {
#pragma unroll
        for (int j = 0; j < 8; j++) tmp[j] = 0;
      }
      *(ushort8*)(&As[r][c_s]) = *(ushort8*)tmp;
      ushort8 vb = {0, 0, 0, 0, 0, 0, 0, 0};
      int gn = n0 + r;
      if (gn < N) vb = *(const ushort8*)(Bt + (size_t)gn * K + k0 + c_s);
      *(ushort8*)(&Bs[r][c_s]) = vb;
    }
    __syncthreads();
    bf16x8 af[4], bfr[4];
#pragma unroll
    for (int mi = 0; mi < 4; mi++) af[mi] = *(const bf16x8*)(&As[wm * 64 + mi * 16 + l16][quad * 8]);
#pragma unroll
    for (int ni = 0; ni < 4; ni++) bfr[ni] = *(const bf16x8*)(&Bs[wn * 64 + ni * 16 + l16][quad * 8]);
#pragma unroll
    for (int mi = 0; mi < 4; mi++)
#pragma unroll
      for (int ni = 0; ni < 4; ni++)
        acc[mi][ni] = __builtin_amdgcn_mfma_f32_16x16x32_bf16(af[mi], bfr[ni], acc[mi][ni], 0, 0, 0);
    __syncthreads();
  }

  if (mode == 1) {
#pragma unroll
    for (int ni = 0; ni < 4; ni++) {
      int gc = n0 + wn * 64 + ni * 16 + l16;
      float bv = bias[gc];
      float part = 0.f;
#pragma unroll
      for (int mi = 0; mi < 4; mi++) {
#pragma unroll
        for (int r = 0; r < 4; r++) {
          int gr = m0 + wm * 64 + mi * 16 + quad * 4 + r;
          if (gr < M) part += tanhf(acc[mi][ni][r] + bv);
        }
      }
      part += __shfl_xor(part, 16);
      part += __shfl_xor(part, 32);
      if (lane < 16) atomicAdd(&colsum[gc], part);
    }
  } else {
#pragma unroll
    for (int ni = 0; ni < 4; ni++) {
      int gc = n0 + wn * 64 + ni * 16 + l16;
      if (gc >= N) continue;
      float bv = bias[gc];
#pragma unroll
      for (int mi = 0; mi < 4; mi++) {
#pragma unroll
        for (int r = 0; r < 4; r++) {
          int gr = m0 + wm * 64 + mi * 16 + quad * 4 + r;
          if (gr < M) {
            float v = acc[mi][ni][r] + bv;
            if (mode == 0) Cb[(size_t)gr * N + gc] = f2bf(v);
            else Cf[(size_t)gr * N + gc] = v;
          }
        }
      }
    }
  }
}

// ---------------- per-node attention logits: o_i[n,h] = sum_d h[n,h*32+d]*a_i[h*32+d] ----------------
__global__ void k_logits(const u16* __restrict__ h, int N,
                         const float* __restrict__ a0, const float* __restrict__ a1,
                         const float* __restrict__ a2, const float* __restrict__ a3,
                         float* __restrict__ o0, float* __restrict__ o1,
                         float* __restrict__ o2, float* __restrict__ o3) {
  int t = blockIdx.x * blockDim.x + threadIdx.x;
  int n = t >> 3, hh = t & 7;
  if (n >= N) return;
  const u16* hp = h + (size_t)n * 256 + hh * 32;
  float d0 = 0.f, d1 = 0.f, d2 = 0.f, d3 = 0.f;
  for (int j = 0; j < 32; j++) {
    float f = bf2f(hp[j]);
    d0 += f * a0[hh * 32 + j];
    d1 += f * a1[hh * 32 + j];
    if (a2) d2 += f * a2[hh * 32 + j];
    if (a3) d3 += f * a3[hh * 32 + j];
  }
  o0[t] = d0;
  o1[t] = d1;
  if (o2) o2[t] = d2;
  if (o3) o3[t] = d3;
}

// ---------------- fused per-(dst,head) softmax + aggregate, one wave per dst ----------------
__global__ __launch_bounds__(256) void k_attn_agg(
    const int* __restrict__ rp, const int* __restrict__ eidx, const int* __restrict__ src,
    const float* __restrict__ als, const float* __restrict__ ald,
    const u16* __restrict__ hsrc, u16* __restrict__ out, int Ndst) {
  int wid = threadIdx.x >> 6, lane = threadIdx.x & 63;
  int n = blockIdx.x * 4 + wid;
  if (n >= Ndst) return;
  int hh = lane >> 3, sub = lane & 7;
  int b = rp[n], e = rp[n + 1];
  float av = ald[n * 8 + hh];
  // pass 1: per-head online max/sum (8 lanes per head, stride-8 over segment)
  float m = -1e30f, s = 0.f;
  for (int i = b + sub; i < e; i += 8) {
    int ed = eidx[i];
    float a = als[src[ed] * 8 + hh] + av;
    a = a > 0.f ? a : 0.2f * a;
    if (a > m) { s = s * expf(m - a) + 1.f; m = a; }
    else s += expf(a - m);
  }
#pragma unroll
  for (int msk = 1; msk < 8; msk <<= 1) {
    float mo = __shfl_xor(m, msk), so = __shfl_xor(s, msk);
    float mn = fmaxf(m, mo);
    s = s * expf(m - mn) + so * expf(mo - mn);
    m = mn;
  }
  float inv = 1.f / (s + 1e-16f);
  // pass 2: weighted gather; lane owns features [lane*4, lane*4+4) (head = lane/8 = hh)
  float a0 = 0.f, a1 = 0.f, a2 = 0.f, a3 = 0.f;
  for (int i = b; i < e; ++i) {
    int ed = eidx[i];
    int sr = src[ed];
    float al = als[sr * 8 + hh] + av;
    al = al > 0.f ? al : 0.2f * al;
    float wv = expf(al - m) * inv;
    ushort4 v = *(const ushort4*)(hsrc + (size_t)sr * 256 + lane * 4);
    a0 += wv * bf2f(v.x);
    a1 += wv * bf2f(v.y);
    a2 += wv * bf2f(v.z);
    a3 += wv * bf2f(v.w);
  }
  ushort4 o;
  o.x = f2bf(a0 > 0.f ? a0 : 0.f);
  o.y = f2bf(a1 > 0.f ? a1 : 0.f);
  o.z = f2bf(a2 > 0.f ? a2 : 0.f);
  o.w = f2bf(a3 > 0.f ? a3 : 0.f);
  *(ushort4*)(out + (size_t)n * 256 + lane * 4) = o;
}

// ---------------- semantic attention scores (K=2) ----------------
__global__ void k_scores(const float* __restrict__ cs0, const float* __restrict__ cs1,
                         const float* __restrict__ q, float invN, float* __restrict__ attn) {
  int lane = threadIdx.x;
  float p0 = 0.f, p1 = 0.f;
  for (int f = lane; f < 256; f += 64) {
    float qv = q[f];
    p0 += qv * cs0[f];
    p1 += qv * cs1[f];
  }
  for (int o = 32; o > 0; o >>= 1) {
    p0 += __shfl_down(p0, o);
    p1 += __shfl_down(p1, o);
  }
  if (lane == 0) {
    float s0 = p0 * invN, s1 = p1 * invN;
    float mx = fmaxf(s0, s1);
    float e0 = expf(s0 - mx), e1 = expf(s1 - mx);
    float den = e0 + e1;
    attn[0] = e0 / den;
    attn[1] = e1 / den;
  }
}

__global__ void k_combine(const u16* __restrict__ x0, const u16* __restrict__ x1,
                          const float* __restrict__ attn, u16* __restrict__ out, int total4) {
  int t = blockIdx.x * blockDim.x + threadIdx.x;
  if (t >= total4) return;
  float a0 = attn[0], a1 = attn[1];
  ushort4 u = ((const ushort4*)x0)[t];
  ushort4 v = ((const ushort4*)x1)[t];
  ushort4 o;
  o.x = f2bf(a0 * bf2f(u.x) + a1 * bf2f(v.x));
  o.y = f2bf(a0 * bf2f(u.y) + a1 * bf2f(v.y));
  o.z = f2bf(a0 * bf2f(u.z) + a1 * bf2f(v.z));
  o.w = f2bf(a0 * bf2f(u.w) + a1 * bf2f(v.w));
  ((ushort4*)out)[t] = o;
}

extern "C" void kernel_launch(void* const* d_in, const int* in_sizes, int n_in,
                              void* d_out, int out_size, void* d_ws, size_t ws_size,
                              hipStream_t stream) {
  const int NP = 100000, NA = 50000;
  const int EAP = 300000, EPA = 300000, EPP = 500000;

  const float* xP = (const float*)d_in[0];
  const float* xA = (const float*)d_in[1];
  const int* srcAP = (const int*)d_in[2];
  const int* dstAP = (const int*)d_in[3];
  const int* srcPA = (const int*)d_in[4];
  const int* dstPA = (const int*)d_in[5];
  const int* srcPP = (const int*)d_in[6];
  const int* dstPP = (const int*)d_in[7];
  const float *W_P[2], *b_P[2], *W_A[2], *b_A[2];
  const float *asAP[2], *adAP[2], *asPA[2], *adPA[2], *asPP[2], *adPP[2];
  const float *kW[2], *kb[2], *qv[2];
  for (int l = 0; l < 2; ++l) {
    int base = 8 + l * 13;
    W_P[l] = (const float*)d_in[base + 0];
    b_P[l] = (const float*)d_in[base + 1];
    W_A[l] = (const float*)d_in[base + 2];
    b_A[l] = (const float*)d_in[base + 3];
    asAP[l] = (const float*)d_in[base + 4];
    adAP[l] = (const float*)d_in[base + 5];
    asPA[l] = (const float*)d_in[base + 6];
    adPA[l] = (const float*)d_in[base + 7];
    asPP[l] = (const float*)d_in[base + 8];
    adPP[l] = (const float*)d_in[base + 9];
    kW[l] = (const float*)d_in[base + 10];
    kb[l] = (const float*)d_in[base + 11];
    qv[l] = (const float*)d_in[base + 12];
  }
  const float* linW = (const float*)d_in[34];
  const float* linb = (const float*)d_in[35];

  // ---------------- workspace layout (~178 MB) ----------------
  char* ws = (char*)d_ws;
  size_t off = 0;
  auto alloc = [&](size_t bytes) -> char* {
    char* p = ws + off;
    off += (bytes + 255) & ~(size_t)255;
    return p;
  };
  u16* P1 = (u16*)alloc((size_t)NP * 256 * 2);
  u16* P2 = (u16*)alloc((size_t)NP * 256 * 2);
  u16* A1 = (u16*)alloc((size_t)NA * 256 * 2);
  u16* A2 = (u16*)alloc((size_t)NA * 256 * 2);
  float* ldAP_P = (float*)alloc((size_t)NP * 8 * 4);
  float* lsPA_P = (float*)alloc((size_t)NP * 8 * 4);
  float* lsPP_P = (float*)alloc((size_t)NP * 8 * 4);
  float* ldPP_P = (float*)alloc((size_t)NP * 8 * 4);
  float* lsAP_A = (float*)alloc((size_t)NA * 8 * 4);
  float* ldPA_A = (float*)alloc((size_t)NA * 8 * 4);
  u16* wtP0 = (u16*)alloc(256 * 512 * 2);
  u16* wtA0 = (u16*)alloc(256 * 256 * 2);
  u16* wtP1 = (u16*)alloc(256 * 256 * 2);
  u16* wtA1 = (u16*)alloc(256 * 256 * 2);
  u16* kwt0 = (u16*)alloc(256 * 256 * 2);
  u16* kwt1 = (u16*)alloc(256 * 256 * 2);
  u16* lwt = (u16*)alloc(32 * 256 * 2);
  int* rpAP = (int*)alloc((NP + 1) * 4);
  int* rpPP = (int*)alloc((NP + 1) * 4);
  int* rpPA = (int*)alloc((NA + 1) * 4);
  int* eiAP = (int*)alloc((size_t)EAP * 4);
  int* eiPP = (int*)alloc((size_t)EPP * 4);
  int* eiPA = (int*)alloc((size_t)EPA * 4);
  size_t zbytes = (size_t)(4 * NP + 2 * NA) * 4 + 4 * 256 * 4;
  char* zblock = alloc(zbytes);
  int* cntAP = (int*)zblock;
  int* cntPP = cntAP + NP;
  int* cntPA = cntPP + NP;
  int* curAP = cntPA + NA;
  int* curPP = curAP + NP;
  int* curPA = curPP + NP;
  float* cs = (float*)(curPA + NA);  // 4 x 256
  float* attnBuf = (float*)alloc(256);

  hipMemsetAsync((void*)zblock, 0, zbytes, stream);

  // weight transposes (f32 -> bf16)
  k_transpose<<<CEILDIV(512 * 256, 256), 256, 0, stream>>>(W_P[0], wtP0, 512, 256);
  k_transpose<<<CEILDIV(256 * 256, 256), 256, 0, stream>>>(W_A[0], wtA0, 256, 256);
  k_transpose<<<CEILDIV(256 * 256, 256), 256, 0, stream>>>(W_P[1], wtP1, 256, 256);
  k_transpose<<<CEILDIV(256 * 256, 256), 256, 0, stream>>>(W_A[1], wtA1, 256, 256);
  k_transpose<<<CEILDIV(256 * 256, 256), 256, 0, stream>>>(kW[0], kwt0, 256, 256);
  k_transpose<<<CEILDIV(256 * 256, 256), 256, 0, stream>>>(kW[1], kwt1, 256, 256);
  k_transpose<<<CEILDIV(256 * 32, 256), 256, 0, stream>>>(linW, lwt, 256, 32);

  // CSR build (by dst), shared by both layers
  k_hist<<<CEILDIV(EAP, 256), 256, 0, stream>>>(dstAP, EAP, cntAP);
  k_hist<<<CEILDIV(EPP, 256), 256, 0, stream>>>(dstPP, EPP, cntPP);
  k_hist<<<CEILDIV(EPA, 256), 256, 0, stream>>>(dstPA, EPA, cntPA);
  k_scan<<<1, 1024, 0, stream>>>(cntAP, rpAP, NP);
  k_scan<<<1, 1024, 0, stream>>>(cntPP, rpPP, NP);
  k_scan<<<1, 1024, 0, stream>>>(cntPA, rpPA, NA);
  k_scatter<<<CEILDIV(EAP, 256), 256, 0, stream>>>(dstAP, EAP, rpAP, curAP, eiAP);
  k_scatter<<<CEILDIV(EPP, 256), 256, 0, stream>>>(dstPP, EPP, rpPP, curPP, eiPP);
  k_scatter<<<CEILDIV(EPA, 256), 256, 0, stream>>>(dstPA, EPA, rpPA, curPA, eiPA);

  auto gemmF = [&](const float* A, const u16* Bt, const float* bias, u16* Cb,
                   int M, int N, int K) {
    dim3 g(CEILDIV(M, BM), CEILDIV(N, BN));
    k_gemm<float><<<g, 256, 0, stream>>>(A, Bt, bias, Cb, nullptr, nullptr, M, N, K, 0);
  };
  auto gemmB = [&](const u16* A, const u16* Bt, const float* bias, u16* Cb, float* Cf,
                   float* colsum, int M, int N, int K, int mode) {
    dim3 g(CEILDIV(M, BM), CEILDIV(N, BN));
    k_gemm<u16><<<g, 256, 0, stream>>>(A, Bt, bias, Cb, Cf, colsum, M, N, K, mode);
  };

  // =================== Layer 0 ===================
  gemmF(xP, wtP0, b_P[0], P1, NP, 256, 512);  // hP -> P1
  gemmF(xA, wtA0, b_A[0], A1, NA, 256, 256);  // hA -> A1
  k_logits<<<CEILDIV(NP * 8, 256), 256, 0, stream>>>(
      P1, NP, adAP[0], asPA[0], asPP[0], adPP[0], ldAP_P, lsPA_P, lsPP_P, ldPP_P);
  k_logits<<<CEILDIV(NA * 8, 256), 256, 0, stream>>>(
      A1, NA, asAP[0], adPA[0], nullptr, nullptr, lsAP_A, ldPA_A, nullptr, nullptr);
  // PP: papers->papers (src hP=P1 -> oPP=P2)
  k_attn_agg<<<CEILDIV(NP, 4), 256, 0, stream>>>(rpPP, eiPP, srcPP, lsPP_P, ldPP_P, P1, P2, NP);
  // PA: papers->authors (src hP=P1 -> oPA=newA=A2)
  k_attn_agg<<<CEILDIV(NA, 4), 256, 0, stream>>>(rpPA, eiPA, srcPA, lsPA_P, ldPA_A, P1, A2, NA);
  // AP: authors->papers (src hA=A1 -> oAP=P1, hP dead now)
  k_attn_agg<<<CEILDIV(NP, 4), 256, 0, stream>>>(rpAP, eiAP, srcAP, lsAP_A, ldAP_P, A1, P1, NP);
  // semantic over {oAP=P1, oPP=P2}
  gemmB(P1, kwt0, kb[0], nullptr, nullptr, cs, NP, 256, 256, 1);
  gemmB(P2, kwt0, kb[0], nullptr, nullptr, cs + 256, NP, 256, 256, 1);
  k_scores<<<1, 64, 0, stream>>>(cs, cs + 256, qv[0], 1.0f / NP, attnBuf);
  k_combine<<<CEILDIV(NP * 64, 256), 256, 0, stream>>>(P1, P2, attnBuf, P1, NP * 64);  // newP0 -> P1

  // =================== Layer 1 ===================
  gemmB(P1, wtP1, b_P[1], P2, nullptr, nullptr, NP, 256, 256, 0);  // hP1 -> P2
  gemmB(A2, wtA1, b_A[1], A1, nullptr, nullptr, NA, 256, 256, 0);  // hA1 -> A1
  k_logits<<<CEILDIV(NP * 8, 256), 256, 0, stream>>>(
      P2, NP, adAP[1], asPA[1], asPP[1], adPP[1], ldAP_P, lsPA_P, lsPP_P, ldPP_P);
  k_logits<<<CEILDIV(NA * 8, 256), 256, 0, stream>>>(
      A1, NA, asAP[1], adPA[1], nullptr, nullptr, lsAP_A, ldPA_A, nullptr, nullptr);
  // PP: src hP1=P2 -> oPP1=P1
  k_attn_agg<<<CEILDIV(NP, 4), 256, 0, stream>>>(rpPP, eiPP, srcPP, lsPP_P, ldPP_P, P2, P1, NP);
  // AP: src hA1=A1 -> oAP1=P2 (hP1 dead now)
  k_attn_agg<<<CEILDIV(NP, 4), 256, 0, stream>>>(rpAP, eiAP, srcAP, lsAP_A, ldAP_P, A1, P2, NP);
  // semantic over {oAP1=P2, oPP1=P1}
  gemmB(P2, kwt1, kb[1], nullptr, nullptr, cs + 512, NP, 256, 256, 1);
  gemmB(P1, kwt1, kb[1], nullptr, nullptr, cs + 768, NP, 256, 256, 1);
  k_scores<<<1, 64, 0, stream>>>(cs + 512, cs + 768, qv[1], 1.0f / NP, attnBuf + 2);
  k_combine<<<CEILDIV(NP * 64, 256), 256, 0, stream>>>(P2, P1, attnBuf + 2, P2, NP * 64);  // newP1 -> P2

  // classifier: d_out[NP,32] (f32) = newP1 @ linW + linb
  gemmB(P2, lwt, linb, nullptr, (float*)d_out, nullptr, NP, 32, 256, 2);
}

// Round 4
// 2401.733 us; speedup vs baseline: 1.0677x; 1.0677x over previous
//
#include <hip/hip_runtime.h>
#include <math.h>

typedef unsigned short u16;
typedef u16 ushort8 __attribute__((ext_vector_type(8)));
typedef __bf16 bf16x8 __attribute__((ext_vector_type(8)));
typedef float floatx4 __attribute__((ext_vector_type(4)));

__device__ __forceinline__ float bf2f(u16 u) {
  union { unsigned int i; float f; } v; v.i = ((unsigned int)u) << 16; return v.f;
}
__device__ __forceinline__ u16 f2bf(float f) {
  union { float f; unsigned int i; } v; v.f = f;
  return (u16)((v.i + 0x7fffu + ((v.i >> 16) & 1u)) >> 16);
}

#define CEILDIV(a, b) (((a) + (b) - 1) / (b))

// ---------------- transpose+convert: W[K][N] (f32) -> Wt[N][K] (bf16) ----------------
__global__ void k_transpose(const float* __restrict__ W, u16* __restrict__ Wt, int K, int N) {
  int t = blockIdx.x * blockDim.x + threadIdx.x;
  if (t >= K * N) return;
  int n = t / K, k = t - n * K;
  Wt[t] = f2bf(W[k * N + n]);
}

// ---------------- CSR build ----------------
__global__ void k_hist(const int* __restrict__ dst, int E, int* __restrict__ cnt) {
  int t = blockIdx.x * blockDim.x + threadIdx.x;
  if (t < E) atomicAdd(&cnt[dst[t]], 1);
}

__global__ __launch_bounds__(1024) void k_scan(const int* __restrict__ cnt, int* __restrict__ rp, int n) {
  __shared__ int sm[1024];
  int t = threadIdx.x;
  int chunk = (n + 1023) >> 10;
  int s = t * chunk, e = min(n, s + chunk);
  int loc = 0;
  for (int i = s; i < e; ++i) loc += cnt[i];
  sm[t] = loc;
  __syncthreads();
  for (int off = 1; off < 1024; off <<= 1) {
    int v = (t >= off) ? sm[t - off] : 0;
    __syncthreads();
    sm[t] += v;
    __syncthreads();
  }
  int base = sm[t] - loc;
  for (int i = s; i < e; ++i) { rp[i] = base; base += cnt[i]; }
  if (t == 1023) rp[n] = sm[1023];
}

__global__ void k_scatter(const int* __restrict__ dst, int E, const int* __restrict__ rp,
                          int* __restrict__ cur, int* __restrict__ eidx) {
  int t = blockIdx.x * blockDim.x + threadIdx.x;
  if (t >= E) return;
  int d = dst[t];
  int p = atomicAdd(&cur[d], 1);
  eidx[rp[d] + p] = t;
}

// ---------------- GEMM: C[M,N] = A[M,K] @ Bt[N,K]^T (+bias), fp32 acc ----------------
// SRC: 0 = f32 A, 1 = bf16 A, 2 = dual bf16 (a0*A + a1*A2, scalars from attn[])
// mode 0: store bf16 Cb. mode 1: tanh(C+bias) colsum atomic. mode 2: store f32 Cf.
#define BM 128
#define BN 128
#define BK 32
#define LDP (BK + 4)  // u16 stride 36 -> word stride 18 (16 distinct banks over rows)

template <int SRC>
__global__ __launch_bounds__(256) void k_gemm(
    const void* __restrict__ Av, const void* __restrict__ A2v, const float* __restrict__ attn,
    const u16* __restrict__ Bt, const float* __restrict__ bias,
    u16* __restrict__ Cb, float* __restrict__ Cf, float* __restrict__ colsum,
    int M, int N, int K, int mode) {
  __shared__ float smemf[2 * BM * LDP / 2];  // 18432 B, aliased as u16 As/Bs
  u16* As = (u16*)smemf;            // [BM][LDP]
  u16* Bs = As + BM * LDP;          // [BN][LDP]

  int tid = threadIdx.x;
  int lane = tid & 63;
  int wid = tid >> 6;
  int wm = wid >> 1, wn = wid & 1;
  int quad = lane >> 4, l16 = lane & 15;
  int m0 = blockIdx.x * BM, n0 = blockIdx.y * BN;

  float a0s = 0.f, a1s = 0.f;
  if (SRC == 2) { a0s = attn[0]; a1s = attn[1]; }

  floatx4 acc[4][4];
#pragma unroll
  for (int i = 0; i < 4; i++)
#pragma unroll
    for (int j = 0; j < 4; j++) acc[i][j] = (floatx4){0.f, 0.f, 0.f, 0.f};

  int r_s = tid >> 2;          // 0..63 (+64 for it=1)
  int c_s = (tid & 3) * 8;     // 0,8,16,24

  auto loadA = [&](int k0, int it) -> ushort8 {
    int gm = m0 + r_s + it * 64;
    ushort8 out = {0, 0, 0, 0, 0, 0, 0, 0};
    if (gm < M) {
      if (SRC == 0) {
        const floatx4* p = (const floatx4*)((const float*)Av + (size_t)gm * K + k0 + c_s);
        floatx4 v0 = p[0], v1 = p[1];
        u16 t[8];
#pragma unroll
        for (int j = 0; j < 4; j++) { t[j] = f2bf(v0[j]); t[4 + j] = f2bf(v1[j]); }
        out = *(ushort8*)t;
      } else if (SRC == 1) {
        out = *(const ushort8*)((const u16*)Av + (size_t)gm * K + k0 + c_s);
      } else {
        ushort8 u = *(const ushort8*)((const u16*)Av + (size_t)gm * K + k0 + c_s);
        ushort8 v = *(const ushort8*)((const u16*)A2v + (size_t)gm * K + k0 + c_s);
        u16 t[8];
#pragma unroll
        for (int j = 0; j < 8; j++) t[j] = f2bf(a0s * bf2f(u[j]) + a1s * bf2f(v[j]));
        out = *(ushort8*)t;
      }
    }
    return out;
  };
  auto loadB = [&](int k0, int it) -> ushort8 {
    int gn = n0 + r_s + it * 64;
    ushort8 out = {0, 0, 0, 0, 0, 0, 0, 0};
    if (gn < N) out = *(const ushort8*)(Bt + (size_t)gn * K + k0 + c_s);
    return out;
  };

  ushort8 ra[2], rb[2];
#pragma unroll
  for (int it = 0; it < 2; ++it) { ra[it] = loadA(0, it); rb[it] = loadB(0, it); }

  for (int k0 = 0; k0 < K; k0 += BK) {
#pragma unroll
    for (int it = 0; it < 2; ++it) {
      int r = r_s + it * 64;
      *(ushort8*)(&As[r * LDP + c_s]) = ra[it];
      *(ushort8*)(&Bs[r * LDP + c_s]) = rb[it];
    }
    __syncthreads();
    bool more = (k0 + BK) < K;
    ushort8 na[2], nb[2];
    if (more) {
#pragma unroll
      for (int it = 0; it < 2; ++it) { na[it] = loadA(k0 + BK, it); nb[it] = loadB(k0 + BK, it); }
    }
    bf16x8 af[4], bfr[4];
#pragma unroll
    for (int mi = 0; mi < 4; mi++)
      af[mi] = *(const bf16x8*)(&As[(wm * 64 + mi * 16 + l16) * LDP + quad * 8]);
#pragma unroll
    for (int ni = 0; ni < 4; ni++)
      bfr[ni] = *(const bf16x8*)(&Bs[(wn * 64 + ni * 16 + l16) * LDP + quad * 8]);
#pragma unroll
    for (int mi = 0; mi < 4; mi++)
#pragma unroll
      for (int ni = 0; ni < 4; ni++)
        acc[mi][ni] = __builtin_amdgcn_mfma_f32_16x16x32_bf16(af[mi], bfr[ni], acc[mi][ni], 0, 0, 0);
    __syncthreads();
    if (more) {
#pragma unroll
      for (int it = 0; it < 2; ++it) { ra[it] = na[it]; rb[it] = nb[it]; }
    }
  }

  if (mode == 1) {
#pragma unroll
    for (int ni = 0; ni < 4; ni++) {
      int gc = n0 + wn * 64 + ni * 16 + l16;
      float bv = bias[gc];
      float part = 0.f;
#pragma unroll
      for (int mi = 0; mi < 4; mi++) {
#pragma unroll
        for (int r = 0; r < 4; r++) {
          int gr = m0 + wm * 64 + mi * 16 + quad * 4 + r;
          if (gr < M) part += tanhf(acc[mi][ni][r] + bv);
        }
      }
      part += __shfl_xor(part, 16);
      part += __shfl_xor(part, 32);
      if (lane < 16) atomicAdd(&colsum[gc], part);
    }
  } else if (mode == 0 && (N & 127) == 0) {
    // LDS transpose epilogue: coalesced 32B/lane row stores
    float* tw = smemf + wid * 16 * 68;  // per-wave 16x68 f32 region (4352B x4 = 17408 <= 18432)
#pragma unroll
    for (int mi = 0; mi < 4; mi++) {
#pragma unroll
      for (int ni = 0; ni < 4; ni++)
#pragma unroll
        for (int r = 0; r < 4; r++)
          tw[(quad * 4 + r) * 68 + ni * 16 + l16] = acc[mi][ni][r];
      int row = lane >> 2, cq = (lane & 3) * 16;
      int gr = m0 + wm * 64 + mi * 16 + row;
      if (gr < M) {
        int gc0 = n0 + wn * 64 + cq;
        u16 ob[16];
#pragma unroll
        for (int j = 0; j < 16; j++) ob[j] = f2bf(tw[row * 68 + cq + j] + bias[gc0 + j]);
        *(ushort8*)(Cb + (size_t)gr * N + gc0) = *(ushort8*)ob;
        *(ushort8*)(Cb + (size_t)gr * N + gc0 + 8) = *(ushort8*)(ob + 8);
      }
    }
  } else {
#pragma unroll
    for (int ni = 0; ni < 4; ni++) {
      int gc = n0 + wn * 64 + ni * 16 + l16;
      if (gc >= N) continue;
      float bv = bias[gc];
#pragma unroll
      for (int mi = 0; mi < 4; mi++) {
#pragma unroll
        for (int r = 0; r < 4; r++) {
          int gr = m0 + wm * 64 + mi * 16 + quad * 4 + r;
          if (gr < M) {
            float v = acc[mi][ni][r] + bv;
            if (mode == 0) Cb[(size_t)gr * N + gc] = f2bf(v);
            else Cf[(size_t)gr * N + gc] = v;
          }
        }
      }
    }
  }
}

// ---------------- per-node attention logits ----------------
__global__ void k_logits(const u16* __restrict__ h, int N,
                         const float* __restrict__ a0, const float* __restrict__ a1,
                         const float* __restrict__ a2, const float* __restrict__ a3,
                         float* __restrict__ o0, float* __restrict__ o1,
                         float* __restrict__ o2, float* __restrict__ o3) {
  int t = blockIdx.x * blockDim.x + threadIdx.x;
  int n = t >> 3, hh = t & 7;
  if (n >= N) return;
  const ushort8* hp = (const ushort8*)(h + (size_t)n * 256 + hh * 32);
  float d0 = 0.f, d1 = 0.f, d2 = 0.f, d3 = 0.f;
#pragma unroll
  for (int q = 0; q < 4; q++) {
    ushort8 v = hp[q];
#pragma unroll
    for (int j = 0; j < 8; j++) {
      float f = bf2f(v[j]);
      int idx = hh * 32 + q * 8 + j;
      d0 += f * a0[idx];
      d1 += f * a1[idx];
      if (a2) d2 += f * a2[idx];
      if (a3) d3 += f * a3[idx];
    }
  }
  o0[t] = d0;
  o1[t] = d1;
  if (o2) o2[t] = d2;
  if (o3) o3[t] = d3;
}

// ---------------- fused per-(dst,head) softmax + aggregate, one wave per dst ----------------
__global__ __launch_bounds__(256) void k_attn_agg(
    const int* __restrict__ rp, const int* __restrict__ eidx, const int* __restrict__ src,
    const float* __restrict__ als, const float* __restrict__ ald,
    const u16* __restrict__ hsrc, u16* __restrict__ out, int Ndst) {
  int wid = threadIdx.x >> 6, lane = threadIdx.x & 63;
  int n = blockIdx.x * 4 + wid;
  if (n >= Ndst) return;
  int hh = lane >> 3, sub = lane & 7;
  int b = rp[n], e = rp[n + 1];
  float av = ald[n * 8 + hh];
  // pass 1: per-head online max/sum, 8 lanes/head, 2-way unrolled stride-16
  float m = -1e30f, s = 0.f;
  {
    int i = b + sub;
    for (; i + 8 < e; i += 16) {
      int e0 = eidx[i], e1 = eidx[i + 8];
      int s0 = src[e0], s1 = src[e1];
      float x0 = als[s0 * 8 + hh] + av, x1 = als[s1 * 8 + hh] + av;
      x0 = x0 > 0.f ? x0 : 0.2f * x0;
      x1 = x1 > 0.f ? x1 : 0.2f * x1;
      float mx = fmaxf(x0, x1);
      float pair = expf(x0 - mx) + expf(x1 - mx);
      if (mx > m) { s = s * expf(m - mx) + pair; m = mx; }
      else s += pair * expf(mx - m);
    }
    if (i < e) {
      int e0 = eidx[i];
      float x0 = als[src[e0] * 8 + hh] + av;
      x0 = x0 > 0.f ? x0 : 0.2f * x0;
      if (x0 > m) { s = s * expf(m - x0) + 1.f; m = x0; }
      else s += expf(x0 - m);
    }
  }
#pragma unroll
  for (int msk = 1; msk < 8; msk <<= 1) {
    float mo = __shfl_xor(m, msk), so = __shfl_xor(s, msk);
    float mn = fmaxf(m, mo);
    s = s * expf(m - mn) + so * expf(mo - mn);
    m = mn;
  }
  float inv = 1.f / (s + 1e-16f);
  // pass 2: weighted gather, 2-way unrolled; lane owns 4 feats (head hh = lane>>3)
  float a0 = 0.f, a1 = 0.f, a2 = 0.f, a3 = 0.f;
  int i = b;
  for (; i + 1 < e; i += 2) {
    int e0 = eidx[i], e1 = eidx[i + 1];
    int s0 = src[e0], s1 = src[e1];
    float x0 = als[s0 * 8 + hh] + av, x1 = als[s1 * 8 + hh] + av;
    ushort4 v0 = *(const ushort4*)(hsrc + (size_t)s0 * 256 + lane * 4);
    ushort4 v1 = *(const ushort4*)(hsrc + (size_t)s1 * 256 + lane * 4);
    x0 = x0 > 0.f ? x0 : 0.2f * x0;
    x1 = x1 > 0.f ? x1 : 0.2f * x1;
    float w0 = expf(x0 - m) * inv, w1 = expf(x1 - m) * inv;
    a0 += w0 * bf2f(v0.x) + w1 * bf2f(v1.x);
    a1 += w0 * bf2f(v0.y) + w1 * bf2f(v1.y);
    a2 += w0 * bf2f(v0.z) + w1 * bf2f(v1.z);
    a3 += w0 * bf2f(v0.w) + w1 * bf2f(v1.w);
  }
  if (i < e) {
    int e0 = eidx[i];
    int s0 = src[e0];
    float x0 = als[s0 * 8 + hh] + av;
    ushort4 v0 = *(const ushort4*)(hsrc + (size_t)s0 * 256 + lane * 4);
    x0 = x0 > 0.f ? x0 : 0.2f * x0;
    float w0 = expf(x0 - m) * inv;
    a0 += w0 * bf2f(v0.x);
    a1 += w0 * bf2f(v0.y);
    a2 += w0 * bf2f(v0.z);
    a3 += w0 * bf2f(v0.w);
  }
  ushort4 o;
  o.x = f2bf(a0 > 0.f ? a0 : 0.f);
  o.y = f2bf(a1 > 0.f ? a1 : 0.f);
  o.z = f2bf(a2 > 0.f ? a2 : 0.f);
  o.w = f2bf(a3 > 0.f ? a3 : 0.f);
  *(ushort4*)(out + (size_t)n * 256 + lane * 4) = o;
}

// ---------------- semantic attention scores (K=2) ----------------
__global__ void k_scores(const float* __restrict__ cs0, const float* __restrict__ cs1,
                         const float* __restrict__ q, float invN, float* __restrict__ attn) {
  int lane = threadIdx.x;
  float p0 = 0.f, p1 = 0.f;
  for (int f = lane; f < 256; f += 64) {
    float qv = q[f];
    p0 += qv * cs0[f];
    p1 += qv * cs1[f];
  }
  for (int o = 32; o > 0; o >>= 1) {
    p0 += __shfl_down(p0, o);
    p1 += __shfl_down(p1, o);
  }
  if (lane == 0) {
    float s0 = p0 * invN, s1 = p1 * invN;
    float mx = fmaxf(s0, s1);
    float e0 = expf(s0 - mx), e1 = expf(s1 - mx);
    float den = e0 + e1;
    attn[0] = e0 / den;
    attn[1] = e1 / den;
  }
}

__global__ void k_combine(const u16* __restrict__ x0, const u16* __restrict__ x1,
                          const float* __restrict__ attn, u16* __restrict__ out, int total8) {
  int t = blockIdx.x * blockDim.x + threadIdx.x;
  if (t >= total8) return;
  float a0 = attn[0], a1 = attn[1];
  ushort8 u = ((const ushort8*)x0)[t];
  ushort8 v = ((const ushort8*)x1)[t];
  u16 o[8];
#pragma unroll
  for (int j = 0; j < 8; j++) o[j] = f2bf(a0 * bf2f(u[j]) + a1 * bf2f(v[j]));
  ((ushort8*)out)[t] = *(ushort8*)o;
}

extern "C" void kernel_launch(void* const* d_in, const int* in_sizes, int n_in,
                              void* d_out, int out_size, void* d_ws, size_t ws_size,
                              hipStream_t stream) {
  const int NP = 100000, NA = 50000;
  const int EAP = 300000, EPA = 300000, EPP = 500000;

  const float* xP = (const float*)d_in[0];
  const float* xA = (const float*)d_in[1];
  const int* srcAP = (const int*)d_in[2];
  const int* dstAP = (const int*)d_in[3];
  const int* srcPA = (const int*)d_in[4];
  const int* dstPA = (const int*)d_in[5];
  const int* srcPP = (const int*)d_in[6];
  const int* dstPP = (const int*)d_in[7];
  const float *W_P[2], *b_P[2], *W_A[2], *b_A[2];
  const float *asAP[2], *adAP[2], *asPA[2], *adPA[2], *asPP[2], *adPP[2];
  const float *kW[2], *kb[2], *qv[2];
  for (int l = 0; l < 2; ++l) {
    int base = 8 + l * 13;
    W_P[l] = (const float*)d_in[base + 0];
    b_P[l] = (const float*)d_in[base + 1];
    W_A[l] = (const float*)d_in[base + 2];
    b_A[l] = (const float*)d_in[base + 3];
    asAP[l] = (const float*)d_in[base + 4];
    adAP[l] = (const float*)d_in[base + 5];
    asPA[l] = (const float*)d_in[base + 6];
    adPA[l] = (const float*)d_in[base + 7];
    asPP[l] = (const float*)d_in[base + 8];
    adPP[l] = (const float*)d_in[base + 9];
    kW[l] = (const float*)d_in[base + 10];
    kb[l] = (const float*)d_in[base + 11];
    qv[l] = (const float*)d_in[base + 12];
  }
  const float* linW = (const float*)d_in[34];
  const float* linb = (const float*)d_in[35];

  // ---------------- workspace layout (~178 MB) ----------------
  char* ws = (char*)d_ws;
  size_t off = 0;
  auto alloc = [&](size_t bytes) -> char* {
    char* p = ws + off;
    off += (bytes + 255) & ~(size_t)255;
    return p;
  };
  u16* P1 = (u16*)alloc((size_t)NP * 256 * 2);
  u16* P2 = (u16*)alloc((size_t)NP * 256 * 2);
  u16* A1 = (u16*)alloc((size_t)NA * 256 * 2);
  u16* A2 = (u16*)alloc((size_t)NA * 256 * 2);
  float* ldAP_P = (float*)alloc((size_t)NP * 8 * 4);
  float* lsPA_P = (float*)alloc((size_t)NP * 8 * 4);
  float* lsPP_P = (float*)alloc((size_t)NP * 8 * 4);
  float* ldPP_P = (float*)alloc((size_t)NP * 8 * 4);
  float* lsAP_A = (float*)alloc((size_t)NA * 8 * 4);
  float* ldPA_A = (float*)alloc((size_t)NA * 8 * 4);
  u16* wtP0 = (u16*)alloc(256 * 512 * 2);
  u16* wtA0 = (u16*)alloc(256 * 256 * 2);
  u16* wtP1 = (u16*)alloc(256 * 256 * 2);
  u16* wtA1 = (u16*)alloc(256 * 256 * 2);
  u16* kwt0 = (u16*)alloc(256 * 256 * 2);
  u16* kwt1 = (u16*)alloc(256 * 256 * 2);
  u16* lwt = (u16*)alloc(32 * 256 * 2);
  int* rpAP = (int*)alloc((NP + 1) * 4);
  int* rpPP = (int*)alloc((NP + 1) * 4);
  int* rpPA = (int*)alloc((NA + 1) * 4);
  int* eiAP = (int*)alloc((size_t)EAP * 4);
  int* eiPP = (int*)alloc((size_t)EPP * 4);
  int* eiPA = (int*)alloc((size_t)EPA * 4);
  size_t zbytes = (size_t)(4 * NP + 2 * NA) * 4 + 4 * 256 * 4;
  char* zblock = alloc(zbytes);
  int* cntAP = (int*)zblock;
  int* cntPP = cntAP + NP;
  int* cntPA = cntPP + NP;
  int* curAP = cntPA + NA;
  int* curPP = curAP + NP;
  int* curPA = curPP + NP;
  float* cs = (float*)(curPA + NA);  // 4 x 256
  float* attnBuf = (float*)alloc(256);

  hipMemsetAsync((void*)zblock, 0, zbytes, stream);

  // weight transposes (f32 -> bf16)
  k_transpose<<<CEILDIV(512 * 256, 256), 256, 0, stream>>>(W_P[0], wtP0, 512, 256);
  k_transpose<<<CEILDIV(256 * 256, 256), 256, 0, stream>>>(W_A[0], wtA0, 256, 256);
  k_transpose<<<CEILDIV(256 * 256, 256), 256, 0, stream>>>(W_P[1], wtP1, 256, 256);
  k_transpose<<<CEILDIV(256 * 256, 256), 256, 0, stream>>>(W_A[1], wtA1, 256, 256);
  k_transpose<<<CEILDIV(256 * 256, 256), 256, 0, stream>>>(kW[0], kwt0, 256, 256);
  k_transpose<<<CEILDIV(256 * 256, 256), 256, 0, stream>>>(kW[1], kwt1, 256, 256);
  k_transpose<<<CEILDIV(256 * 32, 256), 256, 0, stream>>>(linW, lwt, 256, 32);

  // CSR build (by dst), shared by both layers
  k_hist<<<CEILDIV(EAP, 256), 256, 0, stream>>>(dstAP, EAP, cntAP);
  k_hist<<<CEILDIV(EPP, 256), 256, 0, stream>>>(dstPP, EPP, cntPP);
  k_hist<<<CEILDIV(EPA, 256), 256, 0, stream>>>(dstPA, EPA, cntPA);
  k_scan<<<1, 1024, 0, stream>>>(cntAP, rpAP, NP);
  k_scan<<<1, 1024, 0, stream>>>(cntPP, rpPP, NP);
  k_scan<<<1, 1024, 0, stream>>>(cntPA, rpPA, NA);
  k_scatter<<<CEILDIV(EAP, 256), 256, 0, stream>>>(dstAP, EAP, rpAP, curAP, eiAP);
  k_scatter<<<CEILDIV(EPP, 256), 256, 0, stream>>>(dstPP, EPP, rpPP, curPP, eiPP);
  k_scatter<<<CEILDIV(EPA, 256), 256, 0, stream>>>(dstPA, EPA, rpPA, curPA, eiPA);

  auto gemmF = [&](const float* A, const u16* Bt, const float* bias, u16* Cb,
                   int M, int N, int K) {
    dim3 g(CEILDIV(M, BM), CEILDIV(N, BN));
    k_gemm<0><<<g, 256, 0, stream>>>(A, nullptr, nullptr, Bt, bias, Cb, nullptr, nullptr, M, N, K, 0);
  };
  auto gemmB = [&](const u16* A, const u16* Bt, const float* bias, u16* Cb, float* Cf,
                   float* colsum, int M, int N, int K, int mode) {
    dim3 g(CEILDIV(M, BM), CEILDIV(N, BN));
    k_gemm<1><<<g, 256, 0, stream>>>(A, nullptr, nullptr, Bt, bias, Cb, Cf, colsum, M, N, K, mode);
  };
  auto gemmD = [&](const u16* A, const u16* Ab, const float* attn, const u16* Bt,
                   const float* bias, float* Cf, int M, int N, int K) {
    dim3 g(CEILDIV(M, BM), CEILDIV(N, BN));
    k_gemm<2><<<g, 256, 0, stream>>>(A, Ab, attn, Bt, bias, nullptr, Cf, nullptr, M, N, K, 2);
  };

  // =================== Layer 0 ===================
  gemmF(xP, wtP0, b_P[0], P1, NP, 256, 512);  // hP -> P1
  gemmF(xA, wtA0, b_A[0], A1, NA, 256, 256);  // hA -> A1
  k_logits<<<CEILDIV(NP * 8, 256), 256, 0, stream>>>(
      P1, NP, adAP[0], asPA[0], asPP[0], adPP[0], ldAP_P, lsPA_P, lsPP_P, ldPP_P);
  k_logits<<<CEILDIV(NA * 8, 256), 256, 0, stream>>>(
      A1, NA, asAP[0], adPA[0], nullptr, nullptr, lsAP_A, ldPA_A, nullptr, nullptr);
  // PP: papers->papers (src hP=P1 -> oPP=P2)
  k_attn_agg<<<CEILDIV(NP, 4), 256, 0, stream>>>(rpPP, eiPP, srcPP, lsPP_P, ldPP_P, P1, P2, NP);
  // PA: papers->authors (src hP=P1 -> oPA=newA=A2)
  k_attn_agg<<<CEILDIV(NA, 4), 256, 0, stream>>>(rpPA, eiPA, srcPA, lsPA_P, ldPA_A, P1, A2, NA);
  // AP: authors->papers (src hA=A1 -> oAP=P1, hP dead now)
  k_attn_agg<<<CEILDIV(NP, 4), 256, 0, stream>>>(rpAP, eiAP, srcAP, lsAP_A, ldAP_P, A1, P1, NP);
  // semantic over {oAP=P1, oPP=P2}
  gemmB(P1, kwt0, kb[0], nullptr, nullptr, cs, NP, 256, 256, 1);
  gemmB(P2, kwt0, kb[0], nullptr, nullptr, cs + 256, NP, 256, 256, 1);
  k_scores<<<1, 64, 0, stream>>>(cs, cs + 256, qv[0], 1.0f / NP, attnBuf);
  k_combine<<<CEILDIV(NP * 32, 256), 256, 0, stream>>>(P1, P2, attnBuf, P1, NP * 32);  // newP0 -> P1

  // =================== Layer 1 ===================
  gemmB(P1, wtP1, b_P[1], P2, nullptr, nullptr, NP, 256, 256, 0);  // hP1 -> P2
  gemmB(A2, wtA1, b_A[1], A1, nullptr, nullptr, NA, 256, 256, 0);  // hA1 -> A1
  k_logits<<<CEILDIV(NP * 8, 256), 256, 0, stream>>>(
      P2, NP, adAP[1], asPA[1], asPP[1], adPP[1], ldAP_P, lsPA_P, lsPP_P, ldPP_P);
  k_logits<<<CEILDIV(NA * 8, 256), 256, 0, stream>>>(
      A1, NA, asAP[1], adPA[1], nullptr, nullptr, lsAP_A, ldPA_A, nullptr, nullptr);
  // PP: src hP1=P2 -> oPP1=P1
  k_attn_agg<<<CEILDIV(NP, 4), 256, 0, stream>>>(rpPP, eiPP, srcPP, lsPP_P, ldPP_P, P2, P1, NP);
  // AP: src hA1=A1 -> oAP1=P2 (hP1 dead now)
  k_attn_agg<<<CEILDIV(NP, 4), 256, 0, stream>>>(rpAP, eiAP, srcAP, lsAP_A, ldAP_P, A1, P2, NP);
  // semantic over {oAP1=P2, oPP1=P1}
  gemmB(P2, kwt1, kb[1], nullptr, nullptr, cs + 512, NP, 256, 256, 1);
  gemmB(P1, kwt1, kb[1], nullptr, nullptr, cs + 768, NP, 256, 256, 1);
  k_scores<<<1, 64, 0, stream>>>(cs + 512, cs + 768, qv[1], 1.0f / NP, attnBuf + 2);

  // classifier fused with semantic combine: d_out = (a0*P2 + a1*P1) @ linW + linb
  gemmD(P2, P1, attnBuf + 2, lwt, linb, (float*)d_out, NP, 32, 256);
}